// Round 1
// baseline (353.192 us; speedup 1.0000x reference)
//
#include <hip/hip_runtime.h>
#include <hip/hip_bf16.h>

// Problem constants (B,T,C,H) = (4, 2048, 1024, 64)
#define B_ 4
#define T_ 2048
#define C_ 1024
#define H_ 64

// ---------------------------------------------------------------------------
// Kernel 1: fused QKV projection.
// x:[B*T, C] fp32, W*:[C, H] fp32 -> q,k,v:[B*T, H] fp32 in workspace.
// q is pre-scaled by C^-0.5 = 1/32 (reference scales q·k by C^-0.5).
// Block = 256 threads (4 waves); each wave handles 4 rows; thread col = lane.
// Register tile: 4 rows x (q,k,v) -> 48 FMAs per 4-c step vs 16 loads.
// ---------------------------------------------------------------------------
__global__ __launch_bounds__(256) void qkv_proj(
    const float* __restrict__ x,
    const float* __restrict__ Wq,
    const float* __restrict__ Wk,
    const float* __restrict__ Wv,
    float* __restrict__ q_out,
    float* __restrict__ k_out,
    float* __restrict__ v_out)
{
    const int lane = threadIdx.x & 63;
    const int wid  = threadIdx.x >> 6;
    const int row0 = blockIdx.x * 16 + wid * 4;   // 4 consecutive rows per wave

    float accq[4] = {0.f, 0.f, 0.f, 0.f};
    float acck[4] = {0.f, 0.f, 0.f, 0.f};
    float accv[4] = {0.f, 0.f, 0.f, 0.f};

    for (int c = 0; c < C_; c += 4) {
        float4 xv[4];
        #pragma unroll
        for (int r = 0; r < 4; ++r)
            xv[r] = *reinterpret_cast<const float4*>(&x[(size_t)(row0 + r) * C_ + c]);

        #pragma unroll
        for (int j = 0; j < 4; ++j) {
            const float wq = Wq[(size_t)(c + j) * H_ + lane];
            const float wk = Wk[(size_t)(c + j) * H_ + lane];
            const float wv = Wv[(size_t)(c + j) * H_ + lane];
            #pragma unroll
            for (int r = 0; r < 4; ++r) {
                const float xs = reinterpret_cast<const float*>(&xv[r])[j];
                accq[r] += xs * wq;
                acck[r] += xs * wk;
                accv[r] += xs * wv;
            }
        }
    }

    const float qscale = 0.03125f;  // 1024^-0.5
    #pragma unroll
    for (int r = 0; r < 4; ++r) {
        const size_t o = (size_t)(row0 + r) * H_ + lane;
        q_out[o] = accq[r] * qscale;
        k_out[o] = acck[r];
        v_out[o] = accv[r];
    }
}

// ---------------------------------------------------------------------------
// Kernel 2: causal flash attention, fp32.
// Grid (T/4, B); block = 256 thr = 4 waves; wave w handles q-row t0+w.
// Per wave: lane = key within a 64-key LDS tile; q row + out accumulator in
// VGPRs (fully unrolled h). Online softmax: wave-max per tile, rescale only
// when the running max grows. LDS tiles padded to 68 floats/row so that
// ds_read_b128 at float offset 68*s + 4*hq spreads 8 lanes/bank-quad (even).
// ---------------------------------------------------------------------------
__global__ __launch_bounds__(256) void attn_fwd(
    const float* __restrict__ q,
    const float* __restrict__ k,
    const float* __restrict__ v,
    float* __restrict__ out)
{
    __shared__ __align__(16) float ks[64][68];
    __shared__ __align__(16) float vs[64][68];

    const int b    = blockIdx.y;
    const int wid  = threadIdx.x >> 6;
    const int lane = threadIdx.x & 63;
    const int t0   = blockIdx.x * 4;
    const int t    = t0 + wid;

    // q row -> 64 VGPRs (pre-scaled by 1/32 in qkv_proj)
    float qv[64];
    {
        const float4* qp = reinterpret_cast<const float4*>(&q[((size_t)b * T_ + t) * H_]);
        #pragma unroll
        for (int i = 0; i < 16; ++i) {
            const float4 tmp = qp[i];
            qv[4*i+0] = tmp.x; qv[4*i+1] = tmp.y;
            qv[4*i+2] = tmp.z; qv[4*i+3] = tmp.w;
        }
    }

    float acc[64];
    #pragma unroll
    for (int i = 0; i < 64; ++i) acc[i] = 0.f;
    float m = -1e30f;
    float l = 0.f;

    const int kbmax = (t0 + 3) >> 6;   // last key tile needed by any row in block
    for (int kb = 0; kb <= kbmax; ++kb) {
        __syncthreads();   // protect previous tile reads
        // Cooperative stage of 64 keys x 64 h for k and v (float4, coalesced).
        #pragma unroll
        for (int rep = 0; rep < 4; ++rep) {
            const int idx = rep * 256 + threadIdx.x;  // 0..1023
            const int s   = idx >> 4;
            const int hq  = idx & 15;
            const size_t g = ((size_t)b * T_ + (size_t)kb * 64 + s) * H_ + hq * 4;
            *reinterpret_cast<float4*>(&ks[s][hq * 4]) = *reinterpret_cast<const float4*>(&k[g]);
            *reinterpret_cast<float4*>(&vs[s][hq * 4]) = *reinterpret_cast<const float4*>(&v[g]);
        }
        __syncthreads();

        if (kb * 64 <= t) {            // wave-uniform: this tile has keys <= t
            const int s = kb * 64 + lane;
            float score = 0.f;
            #pragma unroll
            for (int hq = 0; hq < 16; ++hq) {
                const float4 kk = *reinterpret_cast<const float4*>(&ks[lane][hq * 4]);
                score += qv[4*hq+0] * kk.x + qv[4*hq+1] * kk.y
                       + qv[4*hq+2] * kk.z + qv[4*hq+3] * kk.w;
            }
            if (s > t) score = -1e30f;  // causal mask

            // wave max of this tile's scores
            float bm = score;
            #pragma unroll
            for (int off = 32; off > 0; off >>= 1)
                bm = fmaxf(bm, __shfl_xor(bm, off));

            if (bm > m) {               // rescale only when running max grows
                const float corr = __expf(m - bm);   // exp(-1e30)=0 on first tile
                l *= corr;
                #pragma unroll
                for (int i = 0; i < 64; ++i) acc[i] *= corr;
                m = bm;
            }

            const float p = __expf(score - m);       // masked lanes -> 0
            l += p;

            #pragma unroll
            for (int hq = 0; hq < 16; ++hq) {
                const float4 vv = *reinterpret_cast<const float4*>(&vs[lane][hq * 4]);
                acc[4*hq+0] += p * vv.x; acc[4*hq+1] += p * vv.y;
                acc[4*hq+2] += p * vv.z; acc[4*hq+3] += p * vv.w;
            }
        }
    }

    // Cross-lane reduction: sum partial out vectors and l over 64 lanes.
    #pragma unroll
    for (int off = 1; off < 64; off <<= 1) {
        l += __shfl_xor(l, off);
        #pragma unroll
        for (int i = 0; i < 64; ++i) acc[i] += __shfl_xor(acc[i], off);
    }

    // lane L stores h = L; pick acc[L] with static-index selects (no scratch).
    float myval = 0.f;
    #pragma unroll
    for (int i = 0; i < 64; ++i)
        if (lane == i) myval = acc[i];

    out[((size_t)b * T_ + t) * H_ + lane] = myval / l;
}

// ---------------------------------------------------------------------------
// Launch. Input order is setup_inputs() dict order: x, Wk, Wq, Wv (note Wk
// before Wq!). Workspace: q,k,v = 3 * B*T*H fp32 = 6 MB.
// ---------------------------------------------------------------------------
extern "C" void kernel_launch(void* const* d_in, const int* in_sizes, int n_in,
                              void* d_out, int out_size, void* d_ws, size_t ws_size,
                              hipStream_t stream)
{
    const float* x  = (const float*)d_in[0];
    const float* Wk = (const float*)d_in[1];
    const float* Wq = (const float*)d_in[2];
    const float* Wv = (const float*)d_in[3];
    float* out = (float*)d_out;

    float* qs = (float*)d_ws;                       // [B*T, H]
    float* ks = qs + (size_t)B_ * T_ * H_;          // [B*T, H]
    float* vsp = ks + (size_t)B_ * T_ * H_;         // [B*T, H]

    qkv_proj<<<dim3((B_ * T_) / 16), dim3(256), 0, stream>>>(x, Wq, Wk, Wv, qs, ks, vsp);
    attn_fwd<<<dim3(T_ / 4, B_), dim3(256), 0, stream>>>(qs, ks, vsp, out);
}